// Round 2
// baseline (474.780 us; speedup 1.0000x reference)
//
#include <hip/hip_runtime.h>

#define TABLE_SIZE 4096
#define BLOCK 256

// clang ext_vector type so __builtin_nontemporal_store accepts it.
typedef float f32x4 __attribute__((ext_vector_type(4)));

__device__ __forceinline__ f32x4 secgelu4(f32x4 v, const float* __restrict__ t)
{
    f32x4 r;
    #pragma unroll
    for (int k = 0; k < 4; ++k) {
        float xv = v[k];
        // X = round-half-even(x * 2^16): rintf in RN mode == np.round
        float X = rintf(xv * 65536.0f);
        // y = floor(X / 64): exact (X integral, /64 is an exponent shift)
        float y = floorf(X * 0.015625f);
        bool  d = (y >= 0.0f);                        // -0.0f >= 0 is true (matches ref)
        float a = fminf(fabsf(y), (float)(TABLE_SIZE - 1));
        r[k] = (d ? xv : 0.0f) - t[(int)a];
    }
    return r;
}

__global__ __launch_bounds__(BLOCK) void secgelu_kernel(
    const float* __restrict__ x, const float* __restrict__ table,
    float* __restrict__ out, int n4, int n)
{
    __shared__ float lds_table[TABLE_SIZE];

    const f32x4* __restrict__ x4 = (const f32x4*)x;
    f32x4* __restrict__ o4 = (f32x4*)out;

    const int stride = gridDim.x * BLOCK;
    int idx = blockIdx.x * BLOCK + threadIdx.x;

    // Prologue: issue the first tile's 4 loads BEFORE table staging, so the
    // HBM read stream starts immediately and its latency hides under the
    // LDS setup + barrier.
    f32x4 v0, v1, v2, v3;
    const bool full = (idx + 3 * stride < n4);
    if (full) {
        v0 = x4[idx];
        v1 = x4[idx + stride];
        v2 = x4[idx + 2 * stride];
        v3 = x4[idx + 3 * stride];
    }

    // Stage the 16 KB table into LDS (coalesced, 16 iters of 256 threads).
    #pragma unroll
    for (int i = threadIdx.x; i < TABLE_SIZE; i += BLOCK)
        lds_table[i] = table[i];
    __syncthreads();

    if (full) {
        for (;;) {
            int next = idx + 4 * stride;
            bool more = (next + 3 * stride < n4);

            // Prefetch the NEXT tile before this tile's stores: keeps 4 KiB
            // of read traffic in flight per wave at all times (MLP).
            f32x4 w0, w1, w2, w3;
            if (more) {
                w0 = x4[next];
                w1 = x4[next + stride];
                w2 = x4[next + 2 * stride];
                w3 = x4[next + 3 * stride];
            }

            f32x4 r0 = secgelu4(v0, lds_table);
            f32x4 r1 = secgelu4(v1, lds_table);
            f32x4 r2 = secgelu4(v2, lds_table);
            f32x4 r3 = secgelu4(v3, lds_table);

            // Nontemporal stores: 268 MB written once, zero reuse — keep the
            // write stream from churning L2/L3.
            __builtin_nontemporal_store(r0, &o4[idx]);
            __builtin_nontemporal_store(r1, &o4[idx + stride]);
            __builtin_nontemporal_store(r2, &o4[idx + 2 * stride]);
            __builtin_nontemporal_store(r3, &o4[idx + 3 * stride]);

            idx = next;
            if (!more) break;
            v0 = w0; v1 = w1; v2 = w2; v3 = w3;
        }
    }

    // Remainder (< 4 strided tiles left; dead for n4 % (4*stride) == 0,
    // which holds at this shape: n4 = 32 * stride).
    for (; idx < n4; idx += stride) {
        f32x4 v = x4[idx];
        __builtin_nontemporal_store(secgelu4(v, lds_table), &o4[idx]);
    }

    // Tail (n not divisible by 4) — dead here, kept for safety.
    int t0 = n4 * 4 + (int)(blockIdx.x * BLOCK + threadIdx.x);
    if (blockIdx.x == 0 && t0 < n) {
        float xv = x[t0];
        float X = rintf(xv * 65536.0f);
        float y = floorf(X * 0.015625f);
        bool  d = (y >= 0.0f);
        float a = fminf(fabsf(y), (float)(TABLE_SIZE - 1));
        out[t0] = (d ? xv : 0.0f) - lds_table[(int)a];
    }
}

extern "C" void kernel_launch(void* const* d_in, const int* in_sizes, int n_in,
                              void* d_out, int out_size, void* d_ws, size_t ws_size,
                              hipStream_t stream) {
    const float* x     = (const float*)d_in[0];
    const float* table = (const float*)d_in[1];
    float* out = (float*)d_out;
    int n  = in_sizes[0];
    int n4 = n / 4;

    // 8 blocks/CU * 256 CUs = 2048 blocks -> 32 waves/CU (LDS caps at 10
    // blocks/CU: 160 KiB / 16 KiB); each thread handles exactly 32 float4s
    // = 8 pipelined unroll-4 tiles.
    int blocks = 2048;
    secgelu_kernel<<<blocks, BLOCK, 0, stream>>>(x, table, out, n4, n);
}

// Round 3
// 465.849 us; speedup vs baseline: 1.0192x; 1.0192x over previous
//
#include <hip/hip_runtime.h>

#define TABLE_SIZE 4096
#define BLOCK 256

// clang ext_vector type so __builtin_nontemporal_store accepts it.
typedef float f32x4 __attribute__((ext_vector_type(4)));

__device__ __forceinline__ f32x4 secgelu4(f32x4 v, const float* __restrict__ t)
{
    f32x4 r;
    #pragma unroll
    for (int k = 0; k < 4; ++k) {
        float xv = v[k];
        // X = round-half-even(x * 2^16): rintf in RN mode == np.round
        float X = rintf(xv * 65536.0f);
        // y = floor(X / 64): exact (X integral, /64 is an exponent shift)
        float y = floorf(X * 0.015625f);
        bool  d = (y >= 0.0f);                        // -0.0f >= 0 true (matches ref)
        float a = fminf(fabsf(y), (float)(TABLE_SIZE - 1));
        r[k] = (d ? xv : 0.0f) - t[(int)a];
    }
    return r;
}

__global__ __launch_bounds__(BLOCK) void secgelu_kernel(
    const float* __restrict__ x, const float* __restrict__ table,
    float* __restrict__ out, int n4, int n)
{
    __shared__ float lds_table[TABLE_SIZE];
    // Stage the 16 KB table into LDS (coalesced, 16 iters of 256 threads).
    #pragma unroll
    for (int i = threadIdx.x; i < TABLE_SIZE; i += BLOCK)
        lds_table[i] = table[i];
    __syncthreads();

    const f32x4* __restrict__ x4 = (const f32x4*)x;
    f32x4* __restrict__ o4 = (f32x4*)out;

    const int stride = gridDim.x * BLOCK;
    int idx = blockIdx.x * BLOCK + threadIdx.x;

    // Main loop: 4x unroll, ALL loads issued unconditionally at the top,
    // stores at the bottom. No branches, no register-carried pipeline —
    // the compiler staggers vmcnt waits per load, so loads 1-3 (and the
    // next iteration's issue) overlap the load->index->LDS-gather->store
    // chain of load 0. ~680 issue-cycles of independent work per wave per
    // 4 KiB read vs ~1000-cycle chain latency, x8 waves/SIMD: fully hidden.
    for (; idx + 3 * stride < n4; idx += 4 * stride) {
        f32x4 v0 = x4[idx];
        f32x4 v1 = x4[idx + stride];
        f32x4 v2 = x4[idx + 2 * stride];
        f32x4 v3 = x4[idx + 3 * stride];

        f32x4 r0 = secgelu4(v0, lds_table);
        f32x4 r1 = secgelu4(v1, lds_table);
        f32x4 r2 = secgelu4(v2, lds_table);
        f32x4 r3 = secgelu4(v3, lds_table);

        // Nontemporal stores: 268 MB written once, zero reuse — don't churn
        // L2/L3 (L3 residency is serving ~half the input reads; protect it).
        __builtin_nontemporal_store(r0, &o4[idx]);
        __builtin_nontemporal_store(r1, &o4[idx + stride]);
        __builtin_nontemporal_store(r2, &o4[idx + 2 * stride]);
        __builtin_nontemporal_store(r3, &o4[idx + 3 * stride]);
    }
    // Remainder (< 4 strided tiles left; dead at this shape — n4 = 32*stride).
    for (; idx < n4; idx += stride) {
        f32x4 v = x4[idx];
        __builtin_nontemporal_store(secgelu4(v, lds_table), &o4[idx]);
    }

    // Tail (n not divisible by 4) — dead here, kept for safety.
    int t0 = n4 * 4 + (int)(blockIdx.x * BLOCK + threadIdx.x);
    if (blockIdx.x == 0 && t0 < n) {
        float xv = x[t0];
        float X = rintf(xv * 65536.0f);
        float y = floorf(X * 0.015625f);
        bool  d = (y >= 0.0f);
        float a = fminf(fabsf(y), (float)(TABLE_SIZE - 1));
        out[t0] = (d ? xv : 0.0f) - lds_table[(int)a];
    }
}

extern "C" void kernel_launch(void* const* d_in, const int* in_sizes, int n_in,
                              void* d_out, int out_size, void* d_ws, size_t ws_size,
                              hipStream_t stream) {
    const float* x     = (const float*)d_in[0];
    const float* table = (const float*)d_in[1];
    float* out = (float*)d_out;
    int n  = in_sizes[0];
    int n4 = n / 4;

    // 2048 blocks = 8 blocks/CU x 256 CU = 32 waves/CU (the HW wave cap;
    // LDS at 16 KB/block and VGPR<=64 are not the limit). Each thread does
    // exactly 32 float4s = 8 unroll-4 iterations, zero remainder.
    int blocks = 2048;
    secgelu_kernel<<<blocks, BLOCK, 0, stream>>>(x, table, out, n4, n);
}